// Round 1
// baseline (783.891 us; speedup 1.0000x reference)
//
#include <hip/hip_runtime.h>
#include <hip/hip_bf16.h>
#include <stdint.h>

// ---------------- problem dims ----------------
#define BTOT   65536
#define DIN    784
#define NH1    256
#define NH2    64
#define NEXP   10
#define BM     64
#define NKS1   25      // K-steps of 32 over 800 (784 zero-padded)
#define NKS2   8       // 256/32

// ---------------- LDS layout (bytes) ----------------
#define XSTRIDE   808                        // bf16 elems per x row (784 + 24 pad)
#define HSTRIDE   264                        // bf16 elems per h row (256 + 8 pad)
#define REGION2   (BM * XSTRIDE * 2)         // 103424: end of x tile
#define W1BUF_B   (NH1 * 40 * 2)             // 20480 per W1 K-tile
#define H_B       (BM * HSTRIDE * 2)         // 33792
#define W2BUF_OFF (REGION2 + H_B)            // 137216
#define W2BUF_B   (NH2 * 40 * 2)             // 5120 per W2 K-tile
#define EXP_OFF   (W2BUF_OFF + 2 * W2BUF_B)  // 147456
#define LDS_TOTAL (EXP_OFF + BM * NEXP * 4)  // 150016

typedef short s16x8 __attribute__((ext_vector_type(8)));
typedef float f32x4 __attribute__((ext_vector_type(4)));

__device__ __forceinline__ void g2l16(const void* g, void* l) {
    __builtin_amdgcn_global_load_lds(
        (const __attribute__((address_space(1))) unsigned char*)g,
        (__attribute__((address_space(3))) unsigned char*)l, 16, 0, 0);
}

// ---------------- prep: transpose + bf16-convert weights into ws ----------------
// W1t: [11][25][256][40] bf16  (expert 10 = gate Wg1); k = ks*32+kk, zero-pad kk>=32 and k>=784
__global__ void prep_w1(const float* __restrict__ W1, const float* __restrict__ Wg1,
                        __bf16* __restrict__ dst) {
    int t = blockIdx.x * 256 + threadIdx.x;
    if (t >= 11 * 25 * 40 * 256) return;
    int n  = t & 255;
    int r  = t >> 8;
    int kk = r % 40; r /= 40;
    int ks = r % 25; r /= 25;
    int e  = r;
    int k = ks * 32 + kk;
    float v = 0.f;
    if (kk < 32 && k < DIN)
        v = (e < NEXP) ? W1[((size_t)e * DIN + k) * NH1 + n] : Wg1[(size_t)k * NH1 + n];
    dst[(((size_t)e * 25 + ks) * NH1 + n) * 40 + kk] = (__bf16)v;
}

// W2t: [10][8][64][40] bf16
__global__ void prep_w2(const float* __restrict__ W2, __bf16* __restrict__ dst) {
    int t = blockIdx.x * 256 + threadIdx.x;
    if (t >= 10 * 8 * 40 * 64) return;
    int n  = t & 63;
    int r  = t >> 6;
    int kk = r % 40; r /= 40;
    int ks = r % 8;  r /= 8;
    int e  = r;
    int k = ks * 32 + kk;
    float v = (kk < 32) ? W2[((size_t)e * NH1 + k) * NH2 + n] : 0.f;
    dst[(((size_t)e * 8 + ks) * NH2 + n) * 40 + kk] = (__bf16)v;
}

// Wg2t: [8][16][40] bf16 (N padded 10->16 with zeros)
__global__ void prep_wg2(const float* __restrict__ Wg2, __bf16* __restrict__ dst) {
    int t = blockIdx.x * 256 + threadIdx.x;
    if (t >= 8 * 16 * 40) return;
    int kk = t % 40;
    int n  = (t / 40) % 16;
    int ks = t / 640;
    int k = ks * 32 + kk;
    float v = (kk < 32 && n < NEXP) ? Wg2[(size_t)k * NEXP + n] : 0.f;
    dst[((size_t)ks * 16 + n) * 40 + kk] = (__bf16)v;
}

// ---------------- fused MoE kernel ----------------
__global__ void __launch_bounds__(256)
moe_fused(const float* __restrict__ x,
          const float* __restrict__ b1, const float* __restrict__ b2,
          const float* __restrict__ W3, const float* __restrict__ b3,
          const float* __restrict__ bg1, const float* __restrict__ bg2,
          const __bf16* __restrict__ w1t,
          const __bf16* __restrict__ w2t,
          const __bf16* __restrict__ wg2t,
          float* __restrict__ out)
{
    extern __shared__ char lds[];
    const int tid  = threadIdx.x;
    const int lane = tid & 63;
    const int wave = tid >> 6;
    const int lr   = lane & 15;
    const int lg   = lane >> 4;
    const int row0 = blockIdx.x * BM;
    const f32x4 fz = {0.f, 0.f, 0.f, 0.f};

    __bf16* xs = (__bf16*)lds;

    // ---- stage x tile fp32 -> bf16 (once; reused by all 11 GEMMs) ----
    {
        const float* xg = x + (size_t)row0 * DIN;
        #pragma unroll 4
        for (int i = 0; i < 49; ++i) {
            int idx = tid + i * 256;             // 49*256 == 64*196 exactly
            int r = idx / 196, c = idx % 196;
            const float4 v = *(const float4*)(xg + (size_t)r * DIN + c * 4);
            __bf16* d = xs + r * XSTRIDE + c * 4;
            d[0] = (__bf16)v.x; d[1] = (__bf16)v.y; d[2] = (__bf16)v.z; d[3] = (__bf16)v.w;
        }
        #pragma unroll
        for (int i = 0; i < 6; ++i) {            // zero-pad cols 784..807
            int idx = tid + i * 256;
            int r = idx / 24, c = DIN + idx % 24;
            xs[r * XSTRIDE + c] = (__bf16)0.f;
        }
    }

    float* expl = (float*)(lds + EXP_OFF);       // [64][10] expert outputs

    for (int e = 0; e <= NEXP; ++e) {
        // ================= layer 1 (expert e, or gate when e==10) =================
        f32x4 acc[4][4];
        #pragma unroll
        for (int mt = 0; mt < 4; ++mt)
            #pragma unroll
            for (int nt = 0; nt < 4; ++nt)
                acc[mt][nt] = fz;

        const __bf16* w1base = w1t + (size_t)e * NKS1 * NH1 * 40;
        {   // prologue stage K-tile 0 into buf0
            const char* src = (const char*)w1base;
            char* dst = lds + REGION2;
            int base = wave * 1024 + lane * 16;
            #pragma unroll
            for (int i = 0; i < 5; ++i)
                g2l16(src + i * 4096 + base, dst + i * 4096 + base);
        }
        __syncthreads();

        for (int ks = 0; ks < NKS1; ++ks) {
            if (ks < NKS1 - 1) {                 // prefetch next K-tile
                const char* src = (const char*)(w1base + (size_t)(ks + 1) * NH1 * 40);
                char* dst = lds + REGION2 + ((ks + 1) & 1) * W1BUF_B;
                int base = wave * 1024 + lane * 16;
                #pragma unroll
                for (int i = 0; i < 5; ++i)
                    g2l16(src + i * 4096 + base, dst + i * 4096 + base);
            }
            const __bf16* wb = (const __bf16*)(lds + REGION2 + (ks & 1) * W1BUF_B);
            s16x8 af[4], bfr[4];
            #pragma unroll
            for (int mt = 0; mt < 4; ++mt)
                af[mt] = *(const s16x8*)(xs + (mt * 16 + lr) * XSTRIDE + ks * 32 + lg * 8);
            #pragma unroll
            for (int nt = 0; nt < 4; ++nt)
                bfr[nt] = *(const s16x8*)(wb + (wave * 64 + nt * 16 + lr) * 40 + lg * 8);
            #pragma unroll
            for (int mt = 0; mt < 4; ++mt)
                #pragma unroll
                for (int nt = 0; nt < 4; ++nt)
                    acc[mt][nt] = __builtin_amdgcn_mfma_f32_16x16x32_bf16(
                        af[mt], bfr[nt], acc[mt][nt], 0, 0, 0);
            __syncthreads();
        }

        // ---- bias + relu -> h (bf16 in LDS); C layout: col=lane&15, row=(lane>>4)*4+reg ----
        const float* bias = (e < NEXP) ? (b1 + e * NH1) : bg1;
        __bf16* h = (__bf16*)(lds + REGION2);
        #pragma unroll
        for (int nt = 0; nt < 4; ++nt) {
            int n = wave * 64 + nt * 16 + lr;
            float bv = bias[n];
            #pragma unroll
            for (int mt = 0; mt < 4; ++mt)
                #pragma unroll
                for (int r = 0; r < 4; ++r) {
                    int m = mt * 16 + lg * 4 + r;
                    h[m * HSTRIDE + n] = (__bf16)fmaxf(acc[mt][nt][r] + bv, 0.f);
                }
        }
        __syncthreads();

        if (e < NEXP) {
            // ================= layer 2: h[64x256] @ W2[e][256x64] =================
            const __bf16* w2base = w2t + (size_t)e * NKS2 * NH2 * 40;
            f32x4 acc2[4];
            #pragma unroll
            for (int jt = 0; jt < 4; ++jt) acc2[jt] = fz;
            {
                const char* src = (const char*)w2base;
                char* dst = lds + W2BUF_OFF;
                for (int c = wave; c < 5; c += 4)
                    g2l16(src + c * 1024 + lane * 16, dst + c * 1024 + lane * 16);
            }
            __syncthreads();
            for (int ks = 0; ks < NKS2; ++ks) {
                if (ks < NKS2 - 1) {
                    const char* src = (const char*)(w2base + (size_t)(ks + 1) * NH2 * 40);
                    char* dst = lds + W2BUF_OFF + ((ks + 1) & 1) * W2BUF_B;
                    for (int c = wave; c < 5; c += 4)
                        g2l16(src + c * 1024 + lane * 16, dst + c * 1024 + lane * 16);
                }
                const __bf16* wb = (const __bf16*)(lds + W2BUF_OFF + (ks & 1) * W2BUF_B);
                s16x8 af = *(const s16x8*)(h + (wave * 16 + lr) * HSTRIDE + ks * 32 + lg * 8);
                #pragma unroll
                for (int jt = 0; jt < 4; ++jt) {
                    s16x8 bf2 = *(const s16x8*)(wb + (jt * 16 + lr) * 40 + lg * 8);
                    acc2[jt] = __builtin_amdgcn_mfma_f32_16x16x32_bf16(af, bf2, acc2[jt], 0, 0, 0);
                }
                __syncthreads();
            }
            // ================= layer 3: relu(h2+b2) . W3 + b3 =================
            const float* b2e = b2 + e * NH2;
            const float* w3e = W3 + e * NH2;
            float part[4] = {0.f, 0.f, 0.f, 0.f};
            #pragma unroll
            for (int jt = 0; jt < 4; ++jt) {
                int col = jt * 16 + lr;
                float bb = b2e[col], ww = w3e[col];
                #pragma unroll
                for (int r = 0; r < 4; ++r)
                    part[r] += fmaxf(acc2[jt][r] + bb, 0.f) * ww;
            }
            #pragma unroll
            for (int off = 1; off < 16; off <<= 1)
                #pragma unroll
                for (int r = 0; r < 4; ++r)
                    part[r] += __shfl_xor(part[r], off, 64);
            if (lr == 0) {
                float bb3 = b3[e];
                #pragma unroll
                for (int r = 0; r < 4; ++r) {
                    int m = wave * 16 + lg * 4 + r;
                    expl[m * NEXP + e] = part[r] + bb3;
                }
            }
        } else {
            // ================= gate: logits = g @ Wg2 + bg2; softmax; combine =================
            {
                const char* src = (const char*)wg2t;      // 10240 B
                char* dst = lds + W2BUF_OFF;
                for (int c = wave; c < 10; c += 4)
                    g2l16(src + c * 1024 + lane * 16, dst + c * 1024 + lane * 16);
            }
            __syncthreads();
            const __bf16* wg = (const __bf16*)(lds + W2BUF_OFF);
            f32x4 acc3 = fz;
            #pragma unroll
            for (int ks = 0; ks < NKS2; ++ks) {
                s16x8 af  = *(const s16x8*)(h + (wave * 16 + lr) * HSTRIDE + ks * 32 + lg * 8);
                s16x8 bf3 = *(const s16x8*)(wg + (ks * 16 + lr) * 40 + lg * 8);
                acc3 = __builtin_amdgcn_mfma_f32_16x16x32_bf16(af, bf3, acc3, 0, 0, 0);
            }
            float bg = (lr < NEXP) ? bg2[lr] : 0.f;
            #pragma unroll
            for (int r = 0; r < 4; ++r) {
                int m = wave * 16 + lg * 4 + r;
                float lv = (lr < NEXP) ? (acc3[r] + bg) : -1e30f;
                float mx = lv;
                #pragma unroll
                for (int off = 1; off < 16; off <<= 1)
                    mx = fmaxf(mx, __shfl_xor(mx, off, 64));
                float p = (lr < NEXP) ? __expf(lv - mx) : 0.f;
                float s = p;
                #pragma unroll
                for (int off = 1; off < 16; off <<= 1)
                    s += __shfl_xor(s, off, 64);
                if (lr < NEXP) {
                    float g  = p / s;
                    float eo = expl[m * NEXP + lr];
                    size_t o = (size_t)(row0 + m) * NEXP + lr;
                    out[o] = g * eo;                       // output
                    out[(size_t)BTOT * NEXP + o] = g;      // gate_scores
                    out[(size_t)2 * BTOT * NEXP + o] = eo; // expert_outputs
                }
            }
        }
    }
}

extern "C" void kernel_launch(void* const* d_in, const int* in_sizes, int n_in,
                              void* d_out, int out_size, void* d_ws, size_t ws_size,
                              hipStream_t stream) {
    (void)in_sizes; (void)n_in; (void)out_size;
    const float* x   = (const float*)d_in[0];
    const float* W1  = (const float*)d_in[1];
    const float* b1  = (const float*)d_in[2];
    const float* W2  = (const float*)d_in[3];
    const float* b2  = (const float*)d_in[4];
    const float* W3  = (const float*)d_in[5];
    const float* b3  = (const float*)d_in[6];
    const float* Wg1 = (const float*)d_in[7];
    const float* bg1 = (const float*)d_in[8];
    const float* Wg2 = (const float*)d_in[9];
    const float* bg2 = (const float*)d_in[10];

    // ws layout (bf16): W1t [11][25][256][40] | W2t [10][8][64][40] | Wg2t [8][16][40]
    // total ~6.06 MB — assumed <= ws_size.
    (void)ws_size;
    __bf16* w1t  = (__bf16*)d_ws;
    __bf16* w2t  = w1t + (size_t)11 * 25 * NH1 * 40;
    __bf16* wg2t = w2t + (size_t)10 * 8 * NH2 * 40;

    hipFuncSetAttribute((const void*)moe_fused,
                        hipFuncAttributeMaxDynamicSharedMemorySize, LDS_TOTAL);

    prep_w1<<<11000, 256, 0, stream>>>(W1, Wg1, w1t);
    prep_w2<<<800, 256, 0, stream>>>(W2, w2t);
    prep_wg2<<<20, 256, 0, stream>>>(Wg2, wg2t);
    moe_fused<<<BTOT / BM, 256, LDS_TOTAL, stream>>>(x, b1, b2, W3, b3, bg1, bg2,
                                                     w1t, w2t, wg2t, (float*)d_out);
}

// Round 2
// 489.295 us; speedup vs baseline: 1.6021x; 1.6021x over previous
//
#include <hip/hip_runtime.h>
#include <hip/hip_bf16.h>
#include <stdint.h>

// ---------------- problem dims ----------------
#define BTOT   65536
#define DIN    784
#define K1P    800     // layer-1 K padded: 784 data + bias row @784 + zeros
#define NH1    256
#define K2P    288     // layer-2/gate K padded: 256 data + bias row @256 + zeros
#define NH2    64
#define NEXP   10
#define BM     64
#define NKS1   25      // 800/32
#define NKS2   9       // 288/32

// ---------------- LDS layout ----------------
// xs [64][808] bf16 (stride 808 elems = 404 words == 20 mod 32 -> per-8-lane
// quad-stride 5 (odd) -> conflict-free b128 reads)
// h  [64][296] bf16 (stride 296 = 148 words == 20 mod 32, same property)
#define XSTRIDE 808
#define HSTRIDE 296
#define H_OFF    (BM * XSTRIDE * 2)            // 103424
#define EXP_OFF  (H_OFF + BM * HSTRIDE * 2)    // 141312
#define LDS_TOTAL (EXP_OFF + BM * NEXP * 4)    // 143872

typedef short s16x8 __attribute__((ext_vector_type(8)));
typedef float f32x4 __attribute__((ext_vector_type(4)));

// ---------------- prep: transpose + bf16 + bias-fold into ws ----------------
// w1t[e][n][k] (e=10 -> gate): k<784: W[k][n]; k==784: bias[n]; else 0.
__global__ void prep_w1(const float* __restrict__ W1, const float* __restrict__ b1,
                        const float* __restrict__ Wg1, const float* __restrict__ bg1,
                        __bf16* __restrict__ dst) {
    int t = blockIdx.x * 256 + threadIdx.x;
    if (t >= 11 * 64 * K1P) return;
    int k  = t % K1P;
    int n4 = (t / K1P) & 63;
    int e  = t / (K1P * 64);
    float4 v = {0.f, 0.f, 0.f, 0.f};
    if (k < DIN) {
        const float* src = (e < NEXP) ? (W1 + ((size_t)e * DIN + k) * NH1)
                                      : (Wg1 + (size_t)k * NH1);
        v = *(const float4*)(src + n4 * 4);
    } else if (k == DIN) {
        const float* src = (e < NEXP) ? (b1 + e * NH1) : bg1;
        v = *(const float4*)(src + n4 * 4);
    }
    size_t base = ((size_t)e * NH1 + n4 * 4) * K1P + k;
    dst[base]           = (__bf16)v.x;
    dst[base + K1P]     = (__bf16)v.y;
    dst[base + 2 * K1P] = (__bf16)v.z;
    dst[base + 3 * K1P] = (__bf16)v.w;
}

// w2t[e][j][k]: k<256: W2[e][k][j]; k==256: b2[e][j]; else 0.
__global__ void prep_w2(const float* __restrict__ W2, const float* __restrict__ b2,
                        __bf16* __restrict__ dst) {
    int t = blockIdx.x * 256 + threadIdx.x;
    if (t >= 10 * 16 * K2P) return;
    int k  = t % K2P;
    int j4 = (t / K2P) & 15;
    int e  = t / (K2P * 16);
    float4 v = {0.f, 0.f, 0.f, 0.f};
    if (k < NH1)       v = *(const float4*)(W2 + ((size_t)e * NH1 + k) * NH2 + j4 * 4);
    else if (k == NH1) v = *(const float4*)(b2 + e * NH2 + j4 * 4);
    size_t base = ((size_t)e * NH2 + j4 * 4) * K2P + k;
    dst[base]           = (__bf16)v.x;
    dst[base + K2P]     = (__bf16)v.y;
    dst[base + 2 * K2P] = (__bf16)v.z;
    dst[base + 3 * K2P] = (__bf16)v.w;
}

// wg2t[j'][k], j' padded 10->16: k<256: Wg2[k][j']; k==256: bg2[j']; else 0.
__global__ void prep_wg2(const float* __restrict__ Wg2, const float* __restrict__ bg2,
                         __bf16* __restrict__ dst) {
    int t = blockIdx.x * 256 + threadIdx.x;
    if (t >= 16 * K2P) return;
    int k = t % K2P;
    int j = t / K2P;
    float v = 0.f;
    if (j < NEXP) {
        if (k < NH1)       v = Wg2[(size_t)k * NEXP + j];
        else if (k == NH1) v = bg2[j];
    }
    dst[(size_t)j * K2P + k] = (__bf16)v;
}

// ---------------- fused MoE kernel ----------------
// Per block: 64 rows, 4 waves. x resident in LDS (read once from HBM).
// Weights stream global->register (L2-resident), reg-double-buffered.
// MFMA operand-swapped: acc = mfma(w_frag, x_frag) -> D[n][m]:
//   lane: m = (lane&15) [tile col], n_local = (lane>>4)*4 + reg [tile row].
// Only 2 barriers per expert.
__global__ void __launch_bounds__(256)
moe_fused(const float* __restrict__ x, const float* __restrict__ W3,
          const float* __restrict__ b3, const __bf16* __restrict__ w1t,
          const __bf16* __restrict__ w2t, const __bf16* __restrict__ wg2t,
          float* __restrict__ out)
{
    extern __shared__ char lds[];
    __bf16* xs   = (__bf16*)lds;
    __bf16* h    = (__bf16*)(lds + H_OFF);
    float*  expl = (float*)(lds + EXP_OFF);

    const int tid  = threadIdx.x;
    const int lane = tid & 63;
    const int wave = tid >> 6;
    const int lr   = lane & 15;
    const int lg   = lane >> 4;
    const int row0 = blockIdx.x * BM;
    const f32x4 fz = {0.f, 0.f, 0.f, 0.f};

    // ---- stage x tile fp32->bf16 (once), packed b64 writes ----
    {
        const float* xg = x + (size_t)row0 * DIN;
        #pragma unroll 4
        for (int i = 0; i < 49; ++i) {               // 49*256 == 64*196
            int idx = tid + i * 256;
            int r = idx / 196, c = (idx % 196) * 4;
            float4 v = *(const float4*)(xg + (size_t)r * DIN + c);
            uint2 w; __bf16* p = (__bf16*)&w;
            p[0] = (__bf16)v.x; p[1] = (__bf16)v.y;
            p[2] = (__bf16)v.z; p[3] = (__bf16)v.w;
            *(uint2*)(xs + r * XSTRIDE + c) = w;
        }
        for (int i = tid; i < 64 * 16; i += 256) {   // cols 784..799: bias-1 + zeros
            int r = i >> 4, c = DIN + (i & 15);
            xs[r * XSTRIDE + c] = (c == DIN) ? (__bf16)1.f : (__bf16)0.f;
        }
        for (int i = tid; i < 64 * 32; i += 256) {   // h cols 256..287 (constant)
            int r = i >> 5, c = NH1 + (i & 31);
            h[r * HSTRIDE + c] = (c == NH1) ? (__bf16)1.f : (__bf16)0.f;
        }
    }
    __syncthreads();

    for (int e = 0; e <= NEXP; ++e) {
        // ================= layer 1 (expert e; e==10 -> gate layer 1) =================
        f32x4 acc[4][4];
        #pragma unroll
        for (int nt = 0; nt < 4; ++nt)
            #pragma unroll
            for (int mt = 0; mt < 4; ++mt) acc[nt][mt] = fz;

        const __bf16* w1e = w1t + ((size_t)e * NH1 + wave * 64 + lr) * K1P + lg * 8;
        s16x8 bc[4], bn[4];
        #pragma unroll
        for (int nt = 0; nt < 4; ++nt)
            bn[nt] = *(const s16x8*)(w1e + nt * 16 * K1P);

        for (int t = 0; t < NKS1; ++t) {
            #pragma unroll
            for (int nt = 0; nt < 4; ++nt) bc[nt] = bn[nt];
            if (t < NKS1 - 1) {
                #pragma unroll
                for (int nt = 0; nt < 4; ++nt)
                    bn[nt] = *(const s16x8*)(w1e + nt * 16 * K1P + (t + 1) * 32);
            }
            s16x8 af[4];
            #pragma unroll
            for (int mt = 0; mt < 4; ++mt)
                af[mt] = *(const s16x8*)(xs + (mt * 16 + lr) * XSTRIDE + t * 32 + lg * 8);
            #pragma unroll
            for (int nt = 0; nt < 4; ++nt)
                #pragma unroll
                for (int mt = 0; mt < 4; ++mt)
                    acc[nt][mt] = __builtin_amdgcn_mfma_f32_16x16x32_bf16(
                        bc[nt], af[mt], acc[nt][mt], 0, 0, 0);
        }

        __syncthreads();   // (1) all waves done reading h of previous expert
        // h[m][n] = relu(C):  value (nt,mt,r) = C[m=mt*16+lr][n=wave*64+nt*16+lg*4+r]
        #pragma unroll
        for (int mt = 0; mt < 4; ++mt)
            #pragma unroll
            for (int nt = 0; nt < 4; ++nt) {
                uint2 w; __bf16* p = (__bf16*)&w;
                #pragma unroll
                for (int r = 0; r < 4; ++r)
                    p[r] = (__bf16)fmaxf(acc[nt][mt][r], 0.f);
                *(uint2*)(h + (mt * 16 + lr) * HSTRIDE + wave * 64 + nt * 16 + lg * 4) = w;
            }
        __syncthreads();   // (2) h ready

        if (e < NEXP) {
            // ================= layer 2 + layer 3 =================
            const __bf16* w2e = w2t + ((size_t)e * NH2 + lr) * K2P + lg * 8;
            f32x4 acc2[4];
            #pragma unroll
            for (int jt = 0; jt < 4; ++jt) acc2[jt] = fz;
            s16x8 wc[4], wn[4];
            #pragma unroll
            for (int jt = 0; jt < 4; ++jt)
                wn[jt] = *(const s16x8*)(w2e + jt * 16 * K2P);
            for (int ks = 0; ks < NKS2; ++ks) {
                #pragma unroll
                for (int jt = 0; jt < 4; ++jt) wc[jt] = wn[jt];
                if (ks < NKS2 - 1) {
                    #pragma unroll
                    for (int jt = 0; jt < 4; ++jt)
                        wn[jt] = *(const s16x8*)(w2e + jt * 16 * K2P + (ks + 1) * 32);
                }
                s16x8 hf = *(const s16x8*)(h + (wave * 16 + lr) * HSTRIDE + ks * 32 + lg * 8);
                #pragma unroll
                for (int jt = 0; jt < 4; ++jt)
                    acc2[jt] = __builtin_amdgcn_mfma_f32_16x16x32_bf16(
                        wc[jt], hf, acc2[jt], 0, 0, 0);
            }
            // layer 3: lane owns m = wave*16+lr, j = jt*16+lg*4+r (b2 folded into acc2)
            float part = 0.f;
            #pragma unroll
            for (int jt = 0; jt < 4; ++jt)
                #pragma unroll
                for (int r = 0; r < 4; ++r) {
                    float w3 = W3[e * NH2 + jt * 16 + lg * 4 + r];
                    part += fmaxf(acc2[jt][r], 0.f) * w3;
                }
            part += __shfl_xor(part, 16, 64);
            part += __shfl_xor(part, 32, 64);
            if (lane < 16)
                expl[(wave * 16 + lr) * NEXP + e] = part + b3[e];
        } else {
            // ================= gate: logits -> softmax -> combine =================
            const __bf16* wge = wg2t + (size_t)lr * K2P + lg * 8;
            f32x4 acc3 = fz;
            for (int ks = 0; ks < NKS2; ++ks) {
                s16x8 gf = *(const s16x8*)(wge + ks * 32);
                s16x8 hf = *(const s16x8*)(h + (wave * 16 + lr) * HSTRIDE + ks * 32 + lg * 8);
                acc3 = __builtin_amdgcn_mfma_f32_16x16x32_bf16(gf, hf, acc3, 0, 0, 0);
            }
            // lane: m = wave*16+lr, expert ep = lg*4+r (bg2 folded)
            const int m = wave * 16 + lr;
            float lv[4], mx = -1e30f;
            #pragma unroll
            for (int r = 0; r < 4; ++r) {
                int ep = lg * 4 + r;
                lv[r] = (ep < NEXP) ? acc3[r] : -1e30f;
                mx = fmaxf(mx, lv[r]);
            }
            mx = fmaxf(mx, __shfl_xor(mx, 16, 64));
            mx = fmaxf(mx, __shfl_xor(mx, 32, 64));
            float p[4], s = 0.f;
            #pragma unroll
            for (int r = 0; r < 4; ++r) {
                int ep = lg * 4 + r;
                p[r] = (ep < NEXP) ? __expf(lv[r] - mx) : 0.f;
                s += p[r];
            }
            s += __shfl_xor(s, 16, 64);
            s += __shfl_xor(s, 32, 64);
            #pragma unroll
            for (int r = 0; r < 4; ++r) {
                int ep = lg * 4 + r;
                if (ep < NEXP) {
                    float g  = p[r] / s;
                    float eo = expl[m * NEXP + ep];
                    size_t o = (size_t)(row0 + m) * NEXP + ep;
                    out[o] = g * eo;                        // output
                    out[(size_t)BTOT * NEXP + o] = g;       // gate_scores
                    out[(size_t)2 * BTOT * NEXP + o] = eo;  // expert_outputs
                }
            }
        }
    }
}

extern "C" void kernel_launch(void* const* d_in, const int* in_sizes, int n_in,
                              void* d_out, int out_size, void* d_ws, size_t ws_size,
                              hipStream_t stream) {
    (void)in_sizes; (void)n_in; (void)out_size; (void)ws_size;
    const float* x   = (const float*)d_in[0];
    const float* W1  = (const float*)d_in[1];
    const float* b1  = (const float*)d_in[2];
    const float* W2  = (const float*)d_in[3];
    const float* b2  = (const float*)d_in[4];
    const float* W3  = (const float*)d_in[5];
    const float* b3  = (const float*)d_in[6];
    const float* Wg1 = (const float*)d_in[7];
    const float* bg1 = (const float*)d_in[8];
    const float* Wg2 = (const float*)d_in[9];
    const float* bg2 = (const float*)d_in[10];

    // ws (bf16): w1t [11][256][800] | w2t [10][64][288] | wg2t [16][288]  (~4.9 MB)
    __bf16* w1t  = (__bf16*)d_ws;
    __bf16* w2t  = w1t + (size_t)11 * NH1 * K1P;
    __bf16* wg2t = w2t + (size_t)10 * NH2 * K2P;

    hipFuncSetAttribute((const void*)moe_fused,
                        hipFuncAttributeMaxDynamicSharedMemorySize, LDS_TOTAL);

    prep_w1<<<(11 * 64 * K1P + 255) / 256, 256, 0, stream>>>(W1, b1, Wg1, bg1, w1t);
    prep_w2<<<(10 * 16 * K2P + 255) / 256, 256, 0, stream>>>(W2, b2, w2t);
    prep_wg2<<<(16 * K2P + 255) / 256, 256, 0, stream>>>(Wg2, bg2, wg2t);
    moe_fused<<<BTOT / BM, 256, LDS_TOTAL, stream>>>(x, W3, b3, w1t, w2t, wg2t,
                                                     (float*)d_out);
}